// Round 1
// baseline (179.869 us; speedup 1.0000x reference)
//
#include <hip/hip_runtime.h>

// GAE: (B=8192, T=256, A=4, 1) fp32.
// delta[b,t,a] = r + GAMMA*nv*(1-term) - v
// g[t] = delta[t] + GAMMA*LMBDA*(1-term[t])*g[t+1],  g[T]=0
// advantages = g, returns = g + v. d_out = [advantages | returns] flat.
//
// Parallel over T via linear-recurrence scan: element (D,K), op
// combine(left,right) = (right.D + right.K*left.D, right.K*left.K).
// One block per b; thread i handles t = T-1-i (so the backward scan is a
// forward scan in i); float4 over the 4 agents -> fully coalesced 16B/lane.

#define GAMMA 0.99f
#define LMBDA 0.95f

constexpr int T = 256;
constexpr int A = 4;

__global__ __launch_bounds__(256) void gae_scan_kernel(
    const float* __restrict__ reward,
    const float* __restrict__ terminated,
    const float* __restrict__ value,
    const float* __restrict__ next_value,
    float* __restrict__ adv_out,
    float* __restrict__ ret_out)
{
    const int b = blockIdx.x;
    const int i = threadIdx.x;          // scan index: i=0 is t=T-1
    const int t = T - 1 - i;
    const int idx = b * T + t;          // float4 index (max 2^21, fits int)

    const float4 r  = ((const float4*)reward)[idx];
    const float4 tm = ((const float4*)terminated)[idx];
    const float4 v  = ((const float4*)value)[idx];
    const float4 nv = ((const float4*)next_value)[idx];

    float vv[4] = {v.x, v.y, v.z, v.w};
    float d[4], k[4];
    {
        float rr[4] = {r.x, r.y, r.z, r.w};
        float tt[4] = {tm.x, tm.y, tm.z, tm.w};
        float nn[4] = {nv.x, nv.y, nv.z, nv.w};
#pragma unroll
        for (int c = 0; c < 4; ++c) {
            float nd = 1.0f - tt[c];
            d[c] = rr[c] + GAMMA * nn[c] * nd - vv[c];
            k[c] = GAMMA * LMBDA * nd;
        }
    }

    const int lane = i & 63;
    const int wave = i >> 6;

    // Wave-level inclusive scan (Hillis-Steele), 6 shuffle steps.
#pragma unroll
    for (int off = 1; off < 64; off <<= 1) {
        float pd[4], pk[4];
#pragma unroll
        for (int c = 0; c < 4; ++c) {
            pd[c] = __shfl_up(d[c], (unsigned)off, 64);
            pk[c] = __shfl_up(k[c], (unsigned)off, 64);
        }
        if (lane >= off) {
#pragma unroll
            for (int c = 0; c < 4; ++c) {
                d[c] = d[c] + k[c] * pd[c];   // combine(prev, cur)
                k[c] = k[c] * pk[c];
            }
        }
    }

    // Cross-wave prefix via LDS (4 waves per block).
    __shared__ float aggD[4][4];  // [wave][chan]
    __shared__ float aggK[4][4];
    if (lane == 63) {
#pragma unroll
        for (int c = 0; c < 4; ++c) { aggD[wave][c] = d[c]; aggK[wave][c] = k[c]; }
    }
    __syncthreads();

    float Dp[4] = {0.f, 0.f, 0.f, 0.f};      // identity: D=0, K=1
    for (int w = 0; w < wave; ++w) {
#pragma unroll
        for (int c = 0; c < 4; ++c) {
            Dp[c] = aggD[w][c] + aggK[w][c] * Dp[c];
        }
    }

    // Final: initial state g[T] = 0 => g = D_total = d + k * Dp.
    float g[4];
#pragma unroll
    for (int c = 0; c < 4; ++c) g[c] = d[c] + k[c] * Dp[c];

    ((float4*)adv_out)[idx] = make_float4(g[0], g[1], g[2], g[3]);
    ((float4*)ret_out)[idx] = make_float4(g[0] + vv[0], g[1] + vv[1],
                                          g[2] + vv[2], g[3] + vv[3]);
}

extern "C" void kernel_launch(void* const* d_in, const int* in_sizes, int n_in,
                              void* d_out, int out_size, void* d_ws, size_t ws_size,
                              hipStream_t stream) {
    const float* reward     = (const float*)d_in[0];
    const float* terminated = (const float*)d_in[1];
    const float* value      = (const float*)d_in[2];
    const float* next_value = (const float*)d_in[3];

    const int B = 8192;
    const int n_elem = B * T * A;           // 8388608
    float* adv = (float*)d_out;
    float* ret = adv + n_elem;

    gae_scan_kernel<<<B, 256, 0, stream>>>(reward, terminated, value,
                                           next_value, adv, ret);
}